// Round 10
// baseline (136.625 us; speedup 1.0000x reference)
//
#include <hip/hip_runtime.h>
#include <hip/hip_fp16.h>
#include <math.h>

#define Bn 512
#define Ln 200
#define En 64
#define Hn 4
#define ITEMS (Bn * Hn)
#define TSZ 3200          // halves per item per tensor (200*16)
#define KS3 18            // fused-path LDS K/Q row stride (odd -> conflict-free)
#define KSG 16            // split-path global K/Q row stride (dense)
#define VS 200            // V^T row stride (halves)
#define QSC 0.36067376022224085f   // 0.25 * log2(e): folds softmax exp into 2^x

typedef _Float16 __f16;
typedef __fp16 fp16x2 __attribute__((ext_vector_type(2)));
typedef __f16 f16x4 __attribute__((ext_vector_type(4)));
typedef __f16 f16x8 __attribute__((ext_vector_type(8)));
typedef float f32x4 __attribute__((ext_vector_type(4)));

#if __has_builtin(__builtin_amdgcn_exp2f)
__device__ __forceinline__ float fexp2(float x) { return __builtin_amdgcn_exp2f(x); }
#else
__device__ __forceinline__ float fexp2(float x) { return exp2f(x); }
#endif

__device__ __forceinline__ f16x8 pack8s(float4 a, float4 b, float4 pa, float4 pb) {
    f16x8 r;
    r[0] = (__f16)(a.x + pa.x); r[1] = (__f16)(a.y + pa.y);
    r[2] = (__f16)(a.z + pa.z); r[3] = (__f16)(a.w + pa.w);
    r[4] = (__f16)(b.x + pb.x); r[5] = (__f16)(b.y + pb.y);
    r[6] = (__f16)(b.z + pb.z); r[7] = (__f16)(b.w + pb.w);
    return r;
}
__device__ __forceinline__ f16x8 pack8(float4 a, float4 b) {
    f16x8 r;
    r[0] = (__f16)a.x; r[1] = (__f16)a.y; r[2] = (__f16)a.z; r[3] = (__f16)a.w;
    r[4] = (__f16)b.x; r[5] = (__f16)b.y; r[6] = (__f16)b.z; r[7] = (__f16)b.w;
    return r;
}
__device__ __forceinline__ f16x4 pack4rtz(float e0, float e1, float e2, float e3) {
    const fp16x2 lo = __builtin_amdgcn_cvt_pkrtz(e0, e1);
    const fp16x2 hi = __builtin_amdgcn_cvt_pkrtz(e2, e3);
    f16x4 r;
    r[0] = (__f16)lo[0]; r[1] = (__f16)lo[1];
    r[2] = (__f16)hi[0]; r[3] = (__f16)hi[1];
    return r;
}

// Attention inner loop. NI = live q-tiles; KS_ = K/Q row stride (18 = LDS path, 16 = global path).
template<int NI, int KS_>
__device__ __forceinline__ void attn_core(
    const __f16* __restrict__ Kh_, const __f16* __restrict__ Qh_, const __f16* __restrict__ Vt_,
    int qt0, int klo, int khi, int nt, int len, int quad, int ln16,
    f32x4 (&o2)[4], f32x4 (&lacc)[4])
{
    const f16x4 ones = {(__f16)1.f, (__f16)1.f, (__f16)1.f, (__f16)1.f};
    f16x4 qf[NI];
    #pragma unroll
    for (int i = 0; i < NI; ++i) {
        int qr = min((qt0 + i) * 16 + ln16, Ln - 1);
        qf[i] = *(const f16x4*)(Qh_ + qr * KS_ + quad * 4);
    }
    const bool needmask = (khi == nt);
    const int kfull = khi - (needmask ? 1 : 0);

    f16x4 kf = *(const f16x4*)(Kh_ + min(klo * 16 + ln16, Ln - 1) * KS_ + quad * 4);
    f16x4 vf = *(const f16x4*)(Vt_ + ln16 * VS + min(klo * 16 + quad * 4, Ln - 4));

    for (int kt = klo; kt < kfull; ++kt) {   // full tiles: no masking
        const int krn = min((kt + 1) * 16 + ln16, Ln - 1);
        const int vcn = min((kt + 1) * 16 + quad * 4, Ln - 4);
        const f16x4 kfn = *(const f16x4*)(Kh_ + krn * KS_ + quad * 4);
        const f16x4 vfn = *(const f16x4*)(Vt_ + ln16 * VS + vcn);
        f32x4 s[NI];
        #pragma unroll
        for (int i = 0; i < NI; ++i)
            s[i] = __builtin_amdgcn_mfma_f32_16x16x16f16(kf, qf[i], (f32x4){0,0,0,0}, 0, 0, 0);
        f16x4 pf[NI];
        #pragma unroll
        for (int i = 0; i < NI; ++i) {
            pf[i] = pack4rtz(fexp2(fminf(s[i][0], 14.5f)),   // 2^14.5 < fp16 max
                             fexp2(fminf(s[i][1], 14.5f)),
                             fexp2(fminf(s[i][2], 14.5f)),
                             fexp2(fminf(s[i][3], 14.5f)));
        }
        #pragma unroll
        for (int i = 0; i < NI; ++i) {
            o2[i]   = __builtin_amdgcn_mfma_f32_16x16x16f16(vf,   pf[i], o2[i],   0, 0, 0);
            lacc[i] = __builtin_amdgcn_mfma_f32_16x16x16f16(ones, pf[i], lacc[i], 0, 0, 0);  // rowsum
        }
        kf = kfn; vf = vfn;
    }
    if (needmask) {   // last tile: zero keys >= len (also neutralizes unwritten/garbage K rows)
        const int kbase = (nt - 1) * 16 + quad * 4;
        f32x4 s[NI];
        #pragma unroll
        for (int i = 0; i < NI; ++i)
            s[i] = __builtin_amdgcn_mfma_f32_16x16x16f16(kf, qf[i], (f32x4){0,0,0,0}, 0, 0, 0);
        f16x4 pf[NI];
        #pragma unroll
        for (int i = 0; i < NI; ++i) {
            float e[4];
            #pragma unroll
            for (int j = 0; j < 4; ++j) {
                const bool kok = (kbase + j) < len;
                e[j] = kok ? fexp2(fminf(s[i][j], 14.5f)) : 0.f;
            }
            pf[i] = pack4rtz(e[0], e[1], e[2], e[3]);
        }
        #pragma unroll
        for (int i = 0; i < NI; ++i) {
            o2[i]   = __builtin_amdgcn_mfma_f32_16x16x16f16(vf,   pf[i], o2[i],   0, 0, 0);
            lacc[i] = __builtin_amdgcn_mfma_f32_16x16x16f16(ones, pf[i], lacc[i], 0, 0, 0);
        }
    }
}

// ================= Kernel A: merged-head projection, pure stream, no LDS/barriers =================
// Block = one b (x read ONCE). 2-deep x pipeline (~128B/lane outstanding: bursty = high BW duty,
// the mechanism the R5 spill run proved). Writes K/Q row-major + V^T fp16 to ws.
__global__ __launch_bounds__(256, 2) void proj_kernel(
    const float* __restrict__ input, const int* __restrict__ mask,
    const float* __restrict__ pos_enc,
    const float* __restrict__ Wk, const float* __restrict__ bk,
    const float* __restrict__ Wv, const float* __restrict__ bv,
    const float* __restrict__ Wq, const float* __restrict__ bq,
    __f16* __restrict__ ws)
{
    const int tid  = threadIdx.x;
    const int b    = blockIdx.x;
    const int wv   = tid >> 6, lane = tid & 63;
    const int quad = lane >> 4, ln16 = lane & 15;

    const float4* in4 = (const float4*)(input + (size_t)b * Ln * En);
    const float4* pe4 = (const float4*)pos_enc;

    // per-wave len (no barrier)
    const int* mb = mask + b * Ln;
    int c = (mb[lane] != 0) + (mb[64 + lane] != 0) + (mb[128 + lane] != 0)
          + ((lane < Ln - 192) ? (mb[192 + lane] != 0) : 0);
    #pragma unroll
    for (int off = 32; off; off >>= 1) c += __shfl_down(c, off, 64);
    const int len = __shfl(c, 0, 64);
    const int nt = (len + 15) >> 4;

    // B-fragments for all 4 heads + biases (L2/L1-hot)
    f16x8 bfr[3][4][2];
    float bz[3][4];
    #pragma unroll
    for (int m = 0; m < 3; ++m) {
        const float* W = (m == 0) ? Wk : (m == 1) ? Wv : Wq;
        const float* B = (m == 0) ? bk : (m == 1) ? bv : bq;
        #pragma unroll
        for (int h = 0; h < 4; ++h) {
            #pragma unroll
            for (int ks = 0; ks < 2; ++ks) {
                const float4* wp = (const float4*)(W + (size_t)(h * 16 + ln16) * 64) + (ks * 8 + quad * 2);
                bfr[m][h][ks] = pack8(wp[0], wp[1]);
            }
            bz[m][h] = B[h * 16 + ln16];
        }
    }

    __f16* Kg = ws;
    __f16* Qg = ws + (size_t)ITEMS * TSZ;
    __f16* Vg = ws + (size_t)2 * ITEMS * TSZ;

#define LDX(rt, A0, A1, A2, A3)                                        \
    {                                                                  \
        A0 = A1 = A2 = A3 = (float4){0, 0, 0, 0};                      \
        const int R_ = (rt) * 16 + ln16;                               \
        if ((rt) < nt && R_ < Ln) {                                    \
            const int o4_ = R_ * 16 + quad * 2;                        \
            A0 = in4[o4_];     A1 = in4[o4_ + 1];                      \
            A2 = in4[o4_ + 8]; A3 = in4[o4_ + 9];                      \
        }                                                              \
    }

    float4 c0, c1, c2, c3, n0, n1, n2, n3, t0, t1, t2, t3;
    LDX(wv,     c0, c1, c2, c3);      // burst: 2 tiles in flight before first consume
    LDX(wv + 4, n0, n1, n2, n3);

    for (int rt = wv; rt < nt; rt += 4) {
        LDX(rt + 8, t0, t1, t2, t3);   // issue tile rt+8 (2-deep cover)

        const int R = rt * 16 + ln16;
        const bool rok = (R < Ln);
        const int o4 = R * 16 + quad * 2;
        float4 p0 = {0,0,0,0}, p1 = {0,0,0,0}, p2 = {0,0,0,0}, p3 = {0,0,0,0};
        if (rok) {
            p0 = pe4[o4];     p1 = pe4[o4 + 1];
            p2 = pe4[o4 + 8]; p3 = pe4[o4 + 9];
        }
        const f16x8 af0 = pack8s(c0, c1, p0, p1);
        const f16x8 af1 = pack8s(c2, c3, p2, p3);

        f32x4 acc[3][4];
        #pragma unroll
        for (int m = 0; m < 3; ++m)
            #pragma unroll
            for (int h = 0; h < 4; ++h)
                acc[m][h] = (f32x4){bz[m][h], bz[m][h], bz[m][h], bz[m][h]};
        #pragma unroll
        for (int m = 0; m < 3; ++m)
            #pragma unroll
            for (int h = 0; h < 4; ++h)
                acc[m][h] = __builtin_amdgcn_mfma_f32_16x16x32_f16(af0, bfr[m][h][0], acc[m][h], 0, 0, 0);
        #pragma unroll
        for (int m = 0; m < 3; ++m)
            #pragma unroll
            for (int h = 0; h < 4; ++h)
                acc[m][h] = __builtin_amdgcn_mfma_f32_16x16x32_f16(af1, bfr[m][h][1], acc[m][h], 0, 0, 0);

        #pragma unroll
        for (int j = 0; j < 4; ++j) {
            const int t = rt * 16 + quad * 4 + j;
            if (t < Ln) {
                #pragma unroll
                for (int h = 0; h < 4; ++h) {
                    const size_t base = (size_t)(b * 4 + h) * TSZ + t * KSG + ln16;
                    Kg[base] = (__f16)acc[0][h][j];
                    Qg[base] = (__f16)(acc[2][h][j] * QSC);
                }
            }
        }
        const int vc0 = rt * 16 + quad * 4;
        if (vc0 < Ln) {
            #pragma unroll
            for (int h = 0; h < 4; ++h) {
                f16x4 vp;
                #pragma unroll
                for (int j = 0; j < 4; ++j) vp[j] = (__f16)acc[1][h][j];
                *(f16x4*)(Vg + (size_t)(b * 4 + h) * TSZ + ln16 * VS + vc0) = vp;
            }
        }
        c0 = n0; c1 = n1; c2 = n2; c3 = n3;
        n0 = t0; n1 = t1; n2 = t2; n3 = t3;
    }
#undef LDX
}

// ================= Kernel B: attention + pool + Wf from ws (L2/L3-hot), tiny LDS =================
// Grid (b,h) = 2048, 256 thr, ~1.3 KB LDS -> 8 blocks/CU = 32 waves/CU (the TLP the fused
// variants never had). K/Q/V fragments read directly from global, prefetched one k-tile ahead.
__global__ __launch_bounds__(256, 4) void attn_kernel(
    const int* __restrict__ mask, const __f16* __restrict__ ws,
    const float* __restrict__ Wf, const float* __restrict__ bf_,
    float* __restrict__ out)
{
    __shared__ float lred[4][4][16];
    __shared__ float red[4][16];
    __shared__ float ph[16];

    const int tid  = threadIdx.x;
    const int item = blockIdx.x;
    const int b    = item >> 2, h = item & 3;
    const int wave = tid >> 6, lane = tid & 63;
    const int quad = lane >> 4, ln16 = lane & 15;

    // per-wave len (no barrier)
    const int* mb = mask + b * Ln;
    int c = (mb[lane] != 0) + (mb[64 + lane] != 0) + (mb[128 + lane] != 0)
          + ((lane < Ln - 192) ? (mb[192 + lane] != 0) : 0);
    #pragma unroll
    for (int off = 32; off; off >>= 1) c += __shfl_down(c, off, 64);
    const int len = __shfl(c, 0, 64);
    const int nt = (len + 15) >> 4;

    const __f16* Kg = ws + (size_t)item * TSZ;
    const __f16* Qg = ws + (size_t)ITEMS * TSZ + (size_t)item * TSZ;
    const __f16* Vg = ws + (size_t)2 * ITEMS * TSZ + (size_t)item * TSZ;

    // adaptive wave assignment over q-quads / key-splits (R0-proven)
    const int nquad = (nt + 3) >> 2;
    int g, kh, nkh;
    if (nquad >= 3)      { g = wave;     kh = 0;         nkh = 1; }
    else if (nquad == 2) { g = wave & 1; kh = wave >> 1; nkh = 2; }
    else                 { g = 0;        kh = wave;      nkh = 4; }
    const bool active = (g < nquad);
    const int nktp = (nt + nkh - 1) / nkh;
    const int klo = kh * nktp;
    const int khi = min(klo + nktp, nt);
    const int qt0 = 4 * g;

    f32x4 o2[4], lacc[4];
    #pragma unroll
    for (int i = 0; i < 4; ++i) { o2[i] = (f32x4){0,0,0,0}; lacc[i] = (f32x4){0,0,0,0}; }

    if (active && klo < khi) {
        const int ni = __builtin_amdgcn_readfirstlane(min(4, nt - qt0));
        switch (ni) {
            case 1:  attn_core<1, KSG>(Kg, Qg, Vg, qt0, klo, khi, nt, len, quad, ln16, o2, lacc); break;
            case 2:  attn_core<2, KSG>(Kg, Qg, Vg, qt0, klo, khi, nt, len, quad, ln16, o2, lacc); break;
            case 3:  attn_core<3, KSG>(Kg, Qg, Vg, qt0, klo, khi, nt, len, quad, ln16, o2, lacc); break;
            default: attn_core<4, KSG>(Kg, Qg, Vg, qt0, klo, khi, nt, len, quad, ln16, o2, lacc); break;
        }
    }

    float l[4];
    #pragma unroll
    for (int i = 0; i < 4; ++i) l[i] = lacc[i][0];

    if (nkh > 1) {   // block-uniform: exchange partial denominators across key-split waves
        if (lane < 16) {
            #pragma unroll
            for (int i = 0; i < 4; ++i) lred[wave][i][lane] = l[i];
        }
        __syncthreads();
        #pragma unroll
        for (int i = 0; i < 4; ++i) {
            if (nkh == 2) l[i] = lred[g][i][ln16] + lred[g + 2][i][ln16];
            else          l[i] = lred[0][i][ln16] + lred[1][i][ln16]
                               + lred[2][i][ln16] + lred[3][i][ln16];
        }
    }

    f32x4 pool = {0.f, 0.f, 0.f, 0.f};
    if (active) {
        #pragma unroll
        for (int i = 0; i < 4; ++i) {
            const float rs = ((qt0 + i) * 16 + ln16 < len) ? 1.f / l[i] : 0.f;
            #pragma unroll
            for (int j = 0; j < 4; ++j) pool[j] = fmaf(o2[i][j], rs, pool[j]);
        }
    }

    #pragma unroll
    for (int j = 0; j < 4; ++j) {
        #pragma unroll
        for (int off = 1; off < 16; off <<= 1) pool[j] += __shfl_xor(pool[j], off, 64);
    }
    if (ln16 == 0) {
        #pragma unroll
        for (int j = 0; j < 4; ++j) red[wave][quad * 4 + j] = pool[j];
    }
    __syncthreads();
    if (tid < 16)
        ph[tid] = (red[0][tid] + red[1][tid] + red[2][tid] + red[3][tid]) / ((float)len + 1e-8f);
    __syncthreads();

    if (tid < 64) {
        const int e = tid;
        const float* wr = Wf + (size_t)e * 64 + h * 16;
        float a = (h == 0) ? bf_[e] : 0.f;
        #pragma unroll
        for (int i = 0; i < 16; ++i) a = fmaf(wr[i], ph[i], a);
        atomicAdd(out + b * En + e, a);
    }
}

// ================= Fallback: R3 fused kernel (43.6 us floor) if ws is too small =================
__global__ __launch_bounds__(256, 4) void fused_kernel(
    const float* __restrict__ input, const int* __restrict__ mask,
    const float* __restrict__ pos_enc,
    const float* __restrict__ Wk, const float* __restrict__ bk,
    const float* __restrict__ Wv, const float* __restrict__ bv,
    const float* __restrict__ Wq, const float* __restrict__ bq,
    const float* __restrict__ Wf, const float* __restrict__ bf_,
    float* __restrict__ out)
{
    __shared__ __align__(16) __f16 Kh[Ln * KS3];
    __shared__ __align__(16) __f16 Qh[Ln * KS3];
    __shared__ __align__(16) __f16 Vt[16 * VS];
    __shared__ float lred[4][4][16];
    __shared__ float red[4][16];
    __shared__ float ph[16];
    __shared__ int cnt_red[4];

    const int tid  = threadIdx.x;
    const int lin  = ((blockIdx.x & 7) << 8) | (blockIdx.x >> 3);
    const int b    = lin >> 2, h = lin & 3;
    const int wave = tid >> 6, lane = tid & 63;
    const int quad = lane >> 4, ln16 = lane & 15;

    const float4* in4 = (const float4*)(input + (size_t)b * Ln * En);
    const float4* pe4 = (const float4*)pos_enc;

    float4 px0 = {0,0,0,0}, px1 = {0,0,0,0}, px2 = {0,0,0,0}, px3 = {0,0,0,0};
    if (wave == 0) {
        const int o4 = ln16 * 16 + quad * 2;
        px0 = in4[o4];     px1 = in4[o4 + 1];
        px2 = in4[o4 + 8]; px3 = in4[o4 + 9];
    }
    const int mv = (tid < Ln) ? mask[b * Ln + tid] : 0;

    f16x8 bfr[3][2];
    #pragma unroll
    for (int m = 0; m < 3; ++m) {
        const float* W = (m == 0) ? Wk : (m == 1) ? Wv : Wq;
        #pragma unroll
        for (int ks = 0; ks < 2; ++ks) {
            const float4* wp = (const float4*)(W + (size_t)(h * 16 + ln16) * 64) + (ks * 8 + quad * 2);
            bfr[m][ks] = pack8(wp[0], wp[1]);
        }
    }
    const int cg = h * 16 + ln16;
    const float bkv = bk[cg], bvv = bv[cg], bqv = bq[cg];

    int c = (mv != 0) ? 1 : 0;
    #pragma unroll
    for (int off = 32; off; off >>= 1) c += __shfl_down(c, off, 64);
    if (lane == 0) cnt_red[wave] = c;
    __syncthreads();
    const int len = cnt_red[0] + cnt_red[1] + cnt_red[2] + cnt_red[3];
    const int nt = (len + 15) >> 4;

    if (wave != 0 && wave < nt) {
        const int o4 = (wave * 16 + ln16) * 16 + quad * 2;
        px0 = in4[o4];     px1 = in4[o4 + 1];
        px2 = in4[o4 + 8]; px3 = in4[o4 + 9];
    }

    for (int rt = wave; rt < nt; rt += 4) {
        const int R = rt * 16 + ln16;
        const bool rok = (R < Ln);
        const int o4 = R * 16 + quad * 2;
        const int rtn = rt + 4;
        const int Rn = rtn * 16 + ln16;
        float4 pxn0 = {0,0,0,0}, pxn1 = {0,0,0,0}, pxn2 = {0,0,0,0}, pxn3 = {0,0,0,0};
        if (rtn < nt && Rn < Ln) {
            const int o4n = Rn * 16 + quad * 2;
            pxn0 = in4[o4n];     pxn1 = in4[o4n + 1];
            pxn2 = in4[o4n + 8]; pxn3 = in4[o4n + 9];
        }
        float4 pp0 = {0,0,0,0}, pp1 = {0,0,0,0}, pp2 = {0,0,0,0}, pp3 = {0,0,0,0};
        if (rok) {
            pp0 = pe4[o4];     pp1 = pe4[o4 + 1];
            pp2 = pe4[o4 + 8]; pp3 = pe4[o4 + 9];
        }
        const f16x8 af0 = pack8s(px0, px1, pp0, pp1);
        const f16x8 af1 = pack8s(px2, px3, pp2, pp3);

        f32x4 acc[3];
        #pragma unroll
        for (int m = 0; m < 3; ++m) acc[m] = (f32x4){0,0,0,0};
        #pragma unroll
        for (int m = 0; m < 3; ++m)
            acc[m] = __builtin_amdgcn_mfma_f32_16x16x32_f16(af0, bfr[m][0], acc[m], 0, 0, 0);
        #pragma unroll
        for (int m = 0; m < 3; ++m)
            acc[m] = __builtin_amdgcn_mfma_f32_16x16x32_f16(af1, bfr[m][1], acc[m], 0, 0, 0);

        #pragma unroll
        for (int j = 0; j < 4; ++j) {
            const int t = rt * 16 + quad * 4 + j;
            if (t < Ln) {
                Kh[t * KS3 + ln16] = (__f16)(acc[0][j] + bkv);
                Qh[t * KS3 + ln16] = (__f16)((acc[2][j] + bqv) * QSC);
            }
        }
        const int vc0 = rt * 16 + quad * 4;
        if (vc0 < Ln) {
            f16x4 vp;
            #pragma unroll
            for (int j = 0; j < 4; ++j) vp[j] = (__f16)(acc[1][j] + bvv);
            *(f16x4*)(Vt + ln16 * VS + vc0) = vp;
        }
        px0 = pxn0; px1 = pxn1; px2 = pxn2; px3 = pxn3;
    }
    __syncthreads();

    const int nquad = (nt + 3) >> 2;
    int g, kh, nkh;
    if (nquad >= 3)      { g = wave;     kh = 0;         nkh = 1; }
    else if (nquad == 2) { g = wave & 1; kh = wave >> 1; nkh = 2; }
    else                 { g = 0;        kh = wave;      nkh = 4; }
    const bool active = (g < nquad);
    const int nktp = (nt + nkh - 1) / nkh;
    const int klo = kh * nktp;
    const int khi = min(klo + nktp, nt);
    const int qt0 = 4 * g;

    f32x4 o2[4], lacc[4];
    #pragma unroll
    for (int i = 0; i < 4; ++i) { o2[i] = (f32x4){0,0,0,0}; lacc[i] = (f32x4){0,0,0,0}; }

    if (active && klo < khi) {
        const int ni = __builtin_amdgcn_readfirstlane(min(4, nt - qt0));
        switch (ni) {
            case 1:  attn_core<1, KS3>(Kh, Qh, Vt, qt0, klo, khi, nt, len, quad, ln16, o2, lacc); break;
            case 2:  attn_core<2, KS3>(Kh, Qh, Vt, qt0, klo, khi, nt, len, quad, ln16, o2, lacc); break;
            case 3:  attn_core<3, KS3>(Kh, Qh, Vt, qt0, klo, khi, nt, len, quad, ln16, o2, lacc); break;
            default: attn_core<4, KS3>(Kh, Qh, Vt, qt0, klo, khi, nt, len, quad, ln16, o2, lacc); break;
        }
    }

    float l[4];
    #pragma unroll
    for (int i = 0; i < 4; ++i) l[i] = lacc[i][0];

    if (nkh > 1) {
        if (lane < 16) {
            #pragma unroll
            for (int i = 0; i < 4; ++i) lred[wave][i][lane] = l[i];
        }
        __syncthreads();
        #pragma unroll
        for (int i = 0; i < 4; ++i) {
            if (nkh == 2) l[i] = lred[g][i][ln16] + lred[g + 2][i][ln16];
            else          l[i] = lred[0][i][ln16] + lred[1][i][ln16]
                               + lred[2][i][ln16] + lred[3][i][ln16];
        }
    }

    f32x4 pool = {0.f, 0.f, 0.f, 0.f};
    if (active) {
        #pragma unroll
        for (int i = 0; i < 4; ++i) {
            const float rs = ((qt0 + i) * 16 + ln16 < len) ? 1.f / l[i] : 0.f;
            #pragma unroll
            for (int j = 0; j < 4; ++j) pool[j] = fmaf(o2[i][j], rs, pool[j]);
        }
    }

    #pragma unroll
    for (int j = 0; j < 4; ++j) {
        #pragma unroll
        for (int off = 1; off < 16; off <<= 1) pool[j] += __shfl_xor(pool[j], off, 64);
    }
    if (ln16 == 0) {
        #pragma unroll
        for (int j = 0; j < 4; ++j) red[wave][quad * 4 + j] = pool[j];
    }
    __syncthreads();
    if (tid < 16)
        ph[tid] = (red[0][tid] + red[1][tid] + red[2][tid] + red[3][tid]) / ((float)len + 1e-8f);
    __syncthreads();

    if (tid < 64) {
        const int e = tid;
        const float* wr = Wf + (size_t)e * 64 + h * 16;
        float a = (h == 0) ? bf_[e] : 0.f;
        #pragma unroll
        for (int i = 0; i < 16; ++i) a = fmaf(wr[i], ph[i], a);
        atomicAdd(out + b * En + e, a);
    }
}

extern "C" void kernel_launch(void* const* d_in, const int* in_sizes, int n_in,
                              void* d_out, int out_size, void* d_ws, size_t ws_size,
                              hipStream_t stream) {
    const float* input   = (const float*)d_in[0];
    const int*   mask    = (const int*)  d_in[1];
    const float* pos_enc = (const float*)d_in[2];
    const float* Wk      = (const float*)d_in[3];
    const float* bk      = (const float*)d_in[4];
    const float* Wv      = (const float*)d_in[5];
    const float* bv      = (const float*)d_in[6];
    const float* Wq      = (const float*)d_in[7];
    const float* bq      = (const float*)d_in[8];
    const float* Wf      = (const float*)d_in[9];
    const float* bf      = (const float*)d_in[10];

    float* out = (float*)d_out;
    hipMemsetAsync(out, 0, (size_t)Bn * En * sizeof(float), stream);   // zero accumulator

    const size_t need = (size_t)3 * ITEMS * TSZ * sizeof(__f16);       // 39.3 MB KQV
    if (ws_size >= need) {
        __f16* ws = (__f16*)d_ws;
        proj_kernel<<<Bn, 256, 0, stream>>>(input, mask, pos_enc,
                                            Wk, bk, Wv, bv, Wq, bq, ws);
        attn_kernel<<<ITEMS, 256, 0, stream>>>(mask, ws, Wf, bf, out);
    } else {
        fused_kernel<<<ITEMS, 256, 0, stream>>>(input, mask, pos_enc,
                                                Wk, bk, Wv, bv, Wq, bq, Wf, bf, out);
    }
}

// Round 12
// 121.085 us; speedup vs baseline: 1.1283x; 1.1283x over previous
//
#include <hip/hip_runtime.h>
#include <hip/hip_fp16.h>
#include <math.h>

#define Bn 512
#define Ln 200
#define En 64
#define Hn 4
#define KS3 18            // Kh/Qh row stride (halves): 36 B = 9 words (odd -> conflict-free)
#define KROWS 208         // Kh padded rows: unclamped prefetch reads rows up to 207 (tile nt-1)
#define VS3 200           // Vt row stride (halves); array padded +16 halves for col overflow
#define QSC 0.36067376022224085f   // 0.25 * log2(e): folds softmax exp into 2^x

typedef _Float16 __f16;
typedef __fp16 fp16x2 __attribute__((ext_vector_type(2)));   // native return type of cvt_pkrtz
typedef __f16 f16x4 __attribute__((ext_vector_type(4)));
typedef __f16 f16x8 __attribute__((ext_vector_type(8)));
typedef float f32x4 __attribute__((ext_vector_type(4)));

#if __has_builtin(__builtin_amdgcn_exp2f)
__device__ __forceinline__ float fexp2(float x) { return __builtin_amdgcn_exp2f(x); }
#else
__device__ __forceinline__ float fexp2(float x) { return exp2f(x); }
#endif

__device__ __forceinline__ f16x8 pack8s(float4 a, float4 b, float4 pa, float4 pb) {
    f16x8 r;
    r[0] = (__f16)(a.x + pa.x); r[1] = (__f16)(a.y + pa.y);
    r[2] = (__f16)(a.z + pa.z); r[3] = (__f16)(a.w + pa.w);
    r[4] = (__f16)(b.x + pb.x); r[5] = (__f16)(b.y + pb.y);
    r[6] = (__f16)(b.z + pb.z); r[7] = (__f16)(b.w + pb.w);
    return r;
}
__device__ __forceinline__ f16x8 pack8(float4 a, float4 b) {
    f16x8 r;
    r[0] = (__f16)a.x; r[1] = (__f16)a.y; r[2] = (__f16)a.z; r[3] = (__f16)a.w;
    r[4] = (__f16)b.x; r[5] = (__f16)b.y; r[6] = (__f16)b.z; r[7] = (__f16)b.w;
    return r;
}
__device__ __forceinline__ f16x4 pack4rtz(float e0, float e1, float e2, float e3) {
    const fp16x2 lo = __builtin_amdgcn_cvt_pkrtz(e0, e1);
    const fp16x2 hi = __builtin_amdgcn_cvt_pkrtz(e2, e3);
    f16x4 r;
    r[0] = (__f16)lo[0]; r[1] = (__f16)lo[1];
    r[2] = (__f16)hi[0]; r[3] = (__f16)hi[1];
    return r;
}

// Attention inner loop, NI = live q-tiles. UNCLAMPED steady-state prefetch: Kh padded to 208
// rows, Vt padded +16 halves, and BOTH pads are ZEROED at kernel start (R11 fix: pad garbage
// is multiplied by pf=0 inside the PV MFMA, and NaN*0=NaN -- garbage K rows are safe via the
// kok SELECT, but V pad must be finite). Removing per-iteration min() clamps cuts ~20% of the
// loop's VALU and lets the compiler strength-reduce LDS addresses to += const induction vars.
template<int NI>
__device__ __forceinline__ void attn_core(
    const __f16* __restrict__ Kh_, const __f16* __restrict__ Qh_, const __f16* __restrict__ Vt_,
    int qt0, int klo, int khi, int nt, int len, int quad, int ln16,
    f32x4 (&o2)[4], f32x4 (&lacc)[4])
{
    const f16x4 ones = {(__f16)1.f, (__f16)1.f, (__f16)1.f, (__f16)1.f};
    f16x4 qf[NI];
    #pragma unroll
    for (int i = 0; i < NI; ++i) {
        int qr = min((qt0 + i) * 16 + ln16, Ln - 1);   // entry-only clamp (4 reads, outside loop)
        qf[i] = *(const f16x4*)(Qh_ + qr * KS3 + quad * 4);
    }
    const bool needmask = (khi == nt);
    const int kfull = khi - (needmask ? 1 : 0);

    // entry loads: rows <= 207 (Kh pad) / cols <= 207 (Vt pad) -- in-bounds, finite (pad zeroed)
    const __f16* kptr = Kh_ + (klo * 16 + ln16) * KS3 + quad * 4;
    const __f16* vptr = Vt_ + ln16 * VS3 + klo * 16 + quad * 4;
    f16x4 kf = *(const f16x4*)kptr;
    f16x4 vf = *(const f16x4*)vptr;

    for (int kt = klo; kt < kfull; ++kt) {   // full tiles: no masking, no clamps
        kptr += 16 * KS3;                     // induction-variable addressing
        vptr += 16;
        const f16x4 kfn = *(const f16x4*)kptr;
        const f16x4 vfn = *(const f16x4*)vptr;
        f32x4 s[NI];
        #pragma unroll
        for (int i = 0; i < NI; ++i)
            s[i] = __builtin_amdgcn_mfma_f32_16x16x16f16(kf, qf[i], (f32x4){0,0,0,0}, 0, 0, 0);
        f16x4 pf[NI];
        #pragma unroll
        for (int i = 0; i < NI; ++i) {
            pf[i] = pack4rtz(fexp2(fminf(s[i][0], 14.5f)),   // 2^14.5 < fp16 max
                             fexp2(fminf(s[i][1], 14.5f)),
                             fexp2(fminf(s[i][2], 14.5f)),
                             fexp2(fminf(s[i][3], 14.5f)));
        }
        #pragma unroll
        for (int i = 0; i < NI; ++i) {
            o2[i]   = __builtin_amdgcn_mfma_f32_16x16x16f16(vf,   pf[i], o2[i],   0, 0, 0);
            lacc[i] = __builtin_amdgcn_mfma_f32_16x16x16f16(ones, pf[i], lacc[i], 0, 0, 0);  // rowsum
        }
        kf = kfn; vf = vfn;
    }
    if (needmask) {   // last tile: zero keys >= len (SELECT; zeroed pads keep V contributions finite)
        const int kbase = (nt - 1) * 16 + quad * 4;
        f32x4 s[NI];
        #pragma unroll
        for (int i = 0; i < NI; ++i)
            s[i] = __builtin_amdgcn_mfma_f32_16x16x16f16(kf, qf[i], (f32x4){0,0,0,0}, 0, 0, 0);
        f16x4 pf[NI];
        #pragma unroll
        for (int i = 0; i < NI; ++i) {
            float e[4];
            #pragma unroll
            for (int j = 0; j < 4; ++j) {
                const bool kok = (kbase + j) < len;
                e[j] = kok ? fexp2(fminf(s[i][j], 14.5f)) : 0.f;
            }
            pf[i] = pack4rtz(e[0], e[1], e[2], e[3]);
        }
        #pragma unroll
        for (int i = 0; i < NI; ++i) {
            o2[i]   = __builtin_amdgcn_mfma_f32_16x16x16f16(vf,   pf[i], o2[i],   0, 0, 0);
            lacc[i] = __builtin_amdgcn_mfma_f32_16x16x16f16(ones, pf[i], lacc[i], 0, 0, 0);
        }
    }
}

// ============ Fully fused (R3 = measured best, harness 121.98): proj + attn + pool + Wf ============
__global__ __launch_bounds__(256, 4) void fused_kernel(
    const float* __restrict__ input, const int* __restrict__ mask,
    const float* __restrict__ pos_enc,
    const float* __restrict__ Wk, const float* __restrict__ bk,
    const float* __restrict__ Wv, const float* __restrict__ bv,
    const float* __restrict__ Wq, const float* __restrict__ bq,
    const float* __restrict__ Wf, const float* __restrict__ bf_,
    float* __restrict__ out)
{
    __shared__ __align__(16) __f16 Kh[KROWS * KS3];     // 7.49 KB  K[t][16] (+8 pad rows)
    __shared__ __align__(16) __f16 Qh[Ln * KS3];        // 7.2 KB   Q[t][16] (pre-scaled QSC)
    __shared__ __align__(16) __f16 Vt[16 * VS3 + 16];   // 6.43 KB  V^T[vd][t] (+16 halves pad)
    __shared__ float lred[4][4][16];                    // 1 KB
    __shared__ float red[4][16];
    __shared__ float ph[16];
    __shared__ int cnt_red[4];

    const int tid  = threadIdx.x;
    // XCD swizzle (2048 = 8 x 256): 4 heads of one b adjacent on one XCD -> input L2 hits
    const int lin  = ((blockIdx.x & 7) << 8) | (blockIdx.x >> 3);
    const int b    = lin >> 2, h = lin & 3;
    const int wave = tid >> 6, lane = tid & 63;
    const int quad = lane >> 4, ln16 = lane & 15;

    // ---- R11 fix: zero the pad regions the unclamped attention prefetch can read.
    // Proj never writes them; the post-proj __syncthreads orders these stores before any read.
    if (tid < 16) Vt[16 * VS3 + tid] = (__f16)0.f;            // V^T col pad (PV-MFMA: NaN*0=NaN)
    if (tid < (KROWS - Ln) * KS3) Kh[Ln * KS3 + tid] = (__f16)0.f;   // K pad rows (144 halves)

    const float4* in4 = (const float4*)(input + (size_t)b * Ln * En);
    const float4* pe4 = (const float4*)pos_enc;

    // ---- speculative first-tile input loads: wave 0 only (tile 0 always needed, nt >= 1) ----
    float4 px0 = {0,0,0,0}, px1 = {0,0,0,0}, px2 = {0,0,0,0}, px3 = {0,0,0,0};
    if (wave == 0) {
        const int o4 = ln16 * 16 + quad * 2;
        px0 = in4[o4];     px1 = in4[o4 + 1];
        px2 = in4[o4 + 8]; px3 = in4[o4 + 9];
    }

    // ---- mask load ----
    const int mv = (tid < Ln) ? mask[b * Ln + tid] : 0;

    // ---- weight B-fragments for THIS head (L2-hot) + biases ----
    f16x8 bfr[3][2];
    #pragma unroll
    for (int m = 0; m < 3; ++m) {
        const float* W = (m == 0) ? Wk : (m == 1) ? Wv : Wq;
        #pragma unroll
        for (int ks = 0; ks < 2; ++ks) {
            const float4* wp = (const float4*)(W + (size_t)(h * 16 + ln16) * 64) + (ks * 8 + quad * 2);
            bfr[m][ks] = pack8(wp[0], wp[1]);
        }
    }
    const int cg = h * 16 + ln16;
    const float bkv = bk[cg], bvv = bv[cg], bqv = bq[cg];

    // ---- len (shuffle reduce over mask) ----
    int c = (mv != 0) ? 1 : 0;
    #pragma unroll
    for (int off = 32; off; off >>= 1) c += __shfl_down(c, off, 64);
    if (lane == 0) cnt_red[wave] = c;
    __syncthreads();
    const int len = cnt_red[0] + cnt_red[1] + cnt_red[2] + cnt_red[3];
    const int nt = (len + 15) >> 4;

    // waves 1..3: first-tile load once nt known (rows <= 63 < Ln: safe)
    if (wave != 0 && wave < nt) {
        const int o4 = (wave * 16 + ln16) * 16 + quad * 2;
        px0 = in4[o4];     px1 = in4[o4 + 1];
        px2 = in4[o4 + 8]; px3 = in4[o4 + 9];
    }

    // ---- projection over nt tiles; software-pipelined input loads ----
    for (int rt = wave; rt < nt; rt += 4) {
        const int R = rt * 16 + ln16;
        const bool rok = (R < Ln);
        const int o4 = R * 16 + quad * 2;

        const int rtn = rt + 4;
        const int Rn = rtn * 16 + ln16;
        float4 pxn0 = {0,0,0,0}, pxn1 = {0,0,0,0}, pxn2 = {0,0,0,0}, pxn3 = {0,0,0,0};
        if (rtn < nt && Rn < Ln) {
            const int o4n = Rn * 16 + quad * 2;
            pxn0 = in4[o4n];     pxn1 = in4[o4n + 1];
            pxn2 = in4[o4n + 8]; pxn3 = in4[o4n + 9];
        }
        float4 pp0 = {0,0,0,0}, pp1 = {0,0,0,0}, pp2 = {0,0,0,0}, pp3 = {0,0,0,0};
        if (rok) {
            pp0 = pe4[o4];     pp1 = pe4[o4 + 1];
            pp2 = pe4[o4 + 8]; pp3 = pe4[o4 + 9];
        }
        const f16x8 af0 = pack8s(px0, px1, pp0, pp1);
        const f16x8 af1 = pack8s(px2, px3, pp2, pp3);

        f32x4 acc[3];
        #pragma unroll
        for (int m = 0; m < 3; ++m) acc[m] = (f32x4){0,0,0,0};
        #pragma unroll
        for (int m = 0; m < 3; ++m)
            acc[m] = __builtin_amdgcn_mfma_f32_16x16x32_f16(af0, bfr[m][0], acc[m], 0, 0, 0);
        #pragma unroll
        for (int m = 0; m < 3; ++m)
            acc[m] = __builtin_amdgcn_mfma_f32_16x16x32_f16(af1, bfr[m][1], acc[m], 0, 0, 0);

        #pragma unroll
        for (int j = 0; j < 4; ++j) {
            const int t = rt * 16 + quad * 4 + j;
            if (t < Ln) {
                Kh[t * KS3 + ln16] = (__f16)(acc[0][j] + bkv);
                Qh[t * KS3 + ln16] = (__f16)((acc[2][j] + bqv) * QSC);
            }
        }
        const int vc0 = rt * 16 + quad * 4;
        if (vc0 < Ln) {
            f16x4 vp;
            #pragma unroll
            for (int j = 0; j < 4; ++j) vp[j] = (__f16)(acc[1][j] + bvv);
            *(f16x4*)(Vt + ln16 * VS3 + vc0) = vp;
        }
        px0 = pxn0; px1 = pxn1; px2 = pxn2; px3 = pxn3;
    }
    __syncthreads();   // K/Q/V (and zeroed pads) visible

    // ---- attention: adaptive wave assignment over q-quads / key-splits ----
    const int nquad = (nt + 3) >> 2;
    int g, kh, nkh;
    if (nquad >= 3)      { g = wave;     kh = 0;         nkh = 1; }
    else if (nquad == 2) { g = wave & 1; kh = wave >> 1; nkh = 2; }
    else                 { g = 0;        kh = wave;      nkh = 4; }
    const bool active = (g < nquad);
    const int nktp = (nt + nkh - 1) / nkh;
    const int klo = kh * nktp;
    const int khi = min(klo + nktp, nt);
    const int qt0 = 4 * g;

    f32x4 o2[4], lacc[4];
    #pragma unroll
    for (int i = 0; i < 4; ++i) { o2[i] = (f32x4){0,0,0,0}; lacc[i] = (f32x4){0,0,0,0}; }

    if (active && klo < khi) {
        const int ni = __builtin_amdgcn_readfirstlane(min(4, nt - qt0));
        switch (ni) {
            case 1:  attn_core<1>(Kh, Qh, Vt, qt0, klo, khi, nt, len, quad, ln16, o2, lacc); break;
            case 2:  attn_core<2>(Kh, Qh, Vt, qt0, klo, khi, nt, len, quad, ln16, o2, lacc); break;
            case 3:  attn_core<3>(Kh, Qh, Vt, qt0, klo, khi, nt, len, quad, ln16, o2, lacc); break;
            default: attn_core<4>(Kh, Qh, Vt, qt0, klo, khi, nt, len, quad, ln16, o2, lacc); break;
        }
    }

    // ---- denominators: lacc[i][0] = l[q=ln16] (replicated across rows by ones-MFMA) ----
    float l[4];
    #pragma unroll
    for (int i = 0; i < 4; ++i) l[i] = lacc[i][0];

    if (nkh > 1) {   // block-uniform: exchange partial denominators across key-split waves
        if (lane < 16) {
            #pragma unroll
            for (int i = 0; i < 4; ++i) lred[wave][i][lane] = l[i];
        }
        __syncthreads();
        #pragma unroll
        for (int i = 0; i < 4; ++i) {
            if (nkh == 2) l[i] = lred[g][i][ln16] + lred[g + 2][i][ln16];
            else          l[i] = lred[0][i][ln16] + lred[1][i][ln16]
                               + lred[2][i][ln16] + lred[3][i][ln16];
        }
    }

    f32x4 pool = {0.f, 0.f, 0.f, 0.f};
    if (active) {
        #pragma unroll
        for (int i = 0; i < 4; ++i) {
            const float rs = ((qt0 + i) * 16 + ln16 < len) ? 1.f / l[i] : 0.f;
            #pragma unroll
            for (int j = 0; j < 4; ++j) pool[j] = fmaf(o2[i][j], rs, pool[j]);
        }
    }

    // ---- reduce pool over 16 q-lanes; combine 4 waves; write ----
    #pragma unroll
    for (int j = 0; j < 4; ++j) {
        #pragma unroll
        for (int off = 1; off < 16; off <<= 1) pool[j] += __shfl_xor(pool[j], off, 64);
    }
    if (ln16 == 0) {
        #pragma unroll
        for (int j = 0; j < 4; ++j) red[wave][quad * 4 + j] = pool[j];
    }
    __syncthreads();
    if (tid < 16)
        ph[tid] = (red[0][tid] + red[1][tid] + red[2][tid] + red[3][tid]) / ((float)len + 1e-8f);
    __syncthreads();

    // ---- fused final projection: partial out[b,e] over i in [h*16, h*16+16) ----
    if (tid < 64) {
        const int e = tid;
        const float* wr = Wf + (size_t)e * 64 + h * 16;
        float a = (h == 0) ? bf_[e] : 0.f;
        #pragma unroll
        for (int i = 0; i < 16; ++i) a = fmaf(wr[i], ph[i], a);
        atomicAdd(out + b * En + e, a);
    }
}

extern "C" void kernel_launch(void* const* d_in, const int* in_sizes, int n_in,
                              void* d_out, int out_size, void* d_ws, size_t ws_size,
                              hipStream_t stream) {
    const float* input   = (const float*)d_in[0];
    const int*   mask    = (const int*)  d_in[1];
    const float* pos_enc = (const float*)d_in[2];
    const float* Wk      = (const float*)d_in[3];
    const float* bk      = (const float*)d_in[4];
    const float* Wv      = (const float*)d_in[5];
    const float* bv      = (const float*)d_in[6];
    const float* Wq      = (const float*)d_in[7];
    const float* bq      = (const float*)d_in[8];
    const float* Wf      = (const float*)d_in[9];
    const float* bf      = (const float*)d_in[10];

    float* out = (float*)d_out;
    hipMemsetAsync(out, 0, (size_t)Bn * En * sizeof(float), stream);   // zero accumulator

    fused_kernel<<<Bn * Hn, 256, 0, stream>>>(input, mask, pos_enc,
                                              Wk, bk, Wv, bv, Wq, bq, Wf, bf, out);
}